// Round 3
// baseline (154.614 us; speedup 1.0000x reference)
//
#include <hip/hip_runtime.h>
#include <math.h>

// StyleGAN2 2x upsample blur (upfirdn2d, up=2, f=[1,3,3,1], gain=4).
// Separable per-axis weights g=[0.25,0.75,0.75,0.25]:
//   out[2i]   = 0.25*X[i-1] + 0.75*X[i]
//   out[2i+1] = 0.75*X[i]   + 0.25*X[i+1]
//
// Layout: block (64,4). Thread (tx,ty) computes 16 outputs:
//   cols ox = blockX*256 + tx + 64*c (c=0..3)  -> lane-contiguous stores
//   rows oy = (blockY*4+ty)*4 + r     (r=0..3)
// Each output col ox (j=ox>>1) needs input cols {j-1,j} (even) or {j,j+1}
// (odd): c0 = j-1+(ox&1), c1 = c0+1, with weights wA,wB by parity.
// Input rows ib-1..ib+2 (ib=oy0>>1) cover the 4 output rows.

__global__ __launch_bounds__(256) void blur_up2_kernel(
    const float* __restrict__ x, float* __restrict__ out,
    int H, int W, int Ho, int Wo) {
    int tx = threadIdx.x;                    // 0..63
    int ty = threadIdx.y;                    // 0..3
    int ox_base = blockIdx.x * 256;
    int oy0 = (blockIdx.y * 4 + ty) * 4;
    int nc = blockIdx.z;
    if (oy0 >= Ho) return;

    const float* xp = x + (size_t)nc * H * W;
    size_t obase = (size_t)nc * Ho * Wo;

    int ib = oy0 >> 1;
    bool yok0 = (ib - 1) >= 0;               // row ib-1
    bool yok3 = (ib + 2) < H;                // row ib+2
    const float* r0 = xp + (ib - 1) * W;
    const float* r1 = xp + ib * W;
    const float* r2 = xp + (ib + 1) * W;
    const float* r3 = xp + (ib + 2) * W;
    // rows ib, ib+1 are always in range (ib in [0, H-2])

    int parity = tx & 1;
    float wA = parity ? 0.75f : 0.25f;
    float wB = parity ? 0.25f : 0.75f;

#pragma unroll
    for (int c = 0; c < 4; ++c) {
        int ox = ox_base + tx + 64 * c;
        int j = ox >> 1;
        int c0 = j - 1 + parity;
        int c1 = c0 + 1;
        bool c0ok = (c0 >= 0) & (c0 < W);
        bool c1ok = (c1 >= 0) & (c1 < W);

        float a00 = (yok0 & c0ok) ? r0[c0] : 0.0f;
        float a01 = (yok0 & c1ok) ? r0[c1] : 0.0f;
        float a10 = c0ok ? r1[c0] : 0.0f;
        float a11 = c1ok ? r1[c1] : 0.0f;
        float a20 = c0ok ? r2[c0] : 0.0f;
        float a21 = c1ok ? r2[c1] : 0.0f;
        float a30 = (yok3 & c0ok) ? r3[c0] : 0.0f;
        float a31 = (yok3 & c1ok) ? r3[c1] : 0.0f;

        // vertical blend for the 4 output rows
        float v00 = 0.25f * a00 + 0.75f * a10;   // row oy0   (even)
        float v01 = 0.25f * a01 + 0.75f * a11;
        float v10 = 0.75f * a10 + 0.25f * a20;   // row oy0+1 (odd)
        float v11 = 0.75f * a11 + 0.25f * a21;
        float v20 = 0.25f * a10 + 0.75f * a20;   // row oy0+2 (even)
        float v21 = 0.25f * a11 + 0.75f * a21;
        float v30 = 0.75f * a20 + 0.25f * a30;   // row oy0+3 (odd)
        float v31 = 0.75f * a21 + 0.25f * a31;

        if (ox < Wo) {
            float* op = out + obase + (size_t)oy0 * Wo + ox;
            op[0] = wA * v00 + wB * v01;
            if (oy0 + 1 < Ho) op[Wo]     = wA * v10 + wB * v11;
            if (oy0 + 2 < Ho) op[2 * Wo] = wA * v20 + wB * v21;
            if (oy0 + 3 < Ho) op[3 * Wo] = wA * v30 + wB * v31;
        }
    }
}

extern "C" void kernel_launch(void* const* d_in, const int* in_sizes, int n_in,
                              void* d_out, int out_size, void* d_ws, size_t ws_size,
                              hipStream_t stream) {
    const float* x = (const float*)d_in[0];
    float* out = (float*)d_out;

    const int H = 256, W = 256;
    int NC = in_sizes[0] / (H * W);  // 256

    int hw_out = out_size / NC;
    int Wo = (int)(sqrt((double)hw_out) + 0.5);
    int Ho = hw_out / Wo;

    dim3 block(64, 4);
    dim3 grid((Wo + 255) / 256, (Ho + 15) / 16, NC);
    blur_up2_kernel<<<grid, block, 0, stream>>>(x, out, H, W, Ho, Wo);
}

// Round 5
// 103.448 us; speedup vs baseline: 1.4946x; 1.4946x over previous
//
#include <hip/hip_runtime.h>
#include <math.h>

// StyleGAN2 2x upsample blur (upfirdn2d, up=2, f=[1,3,3,1], gain=4).
// Separable per-axis weights g=[0.25,0.75,0.75,0.25]:
//   out[2i]   = 0.25*X[i-1] + 0.75*X[i]
//   out[2i+1] = 0.75*X[i]   + 0.25*X[i+1]
//
// Block (64,4): wave = 64 lanes (ty uniform per wave). Thread (tx,ty):
//   cols ox = blockX*256 + 64*g + tx (g=0..3)  -> stores 256B-contiguous/wave
//   rows oy = (blockY*4+ty)*4 + r    (r=0..3)
// All loads are UNCONDITIONAL with addresses clamped into [0,W-1]/[0,H-1];
// boundary handling via masks folded into blend weights (wave-uniform row
// masks w0/w3, single left-edge column mask mL). Lanes whose ox >= Wo load
// clamped-but-in-bounds data and never store. All 32 loads issue before any
// compute -> full memory-level parallelism.

__global__ __launch_bounds__(256) void blur_up2_kernel(
    const float* __restrict__ x, float* __restrict__ out,
    int H, int W, int Ho, int Wo) {
    int tx = threadIdx.x;                    // 0..63
    int ty = threadIdx.y;                    // 0..3
    int ox_base = blockIdx.x * 256;
    int oy0 = (blockIdx.y * 4 + ty) * 4;
    int nc = blockIdx.z;
    if (oy0 >= Ho) return;

    const float* xp = x + (size_t)nc * H * W;
    size_t obase = (size_t)nc * Ho * Wo;

    int ib = oy0 >> 1;                       // rows ib-1..ib+2 needed
    int r0i = ib - 1 < 0 ? 0 : ib - 1;
    int r3i = ib + 2 > H - 1 ? H - 1 : ib + 2;
    const float* r0 = xp + r0i * W;
    const float* r1 = xp + ib * W;
    const float* r2 = xp + (ib + 1) * W;
    const float* r3 = xp + r3i * W;
    float w0 = (ib >= 1)         ? 0.25f : 0.0f; // row masks folded in weights
    float w3 = (ib + 2 <= H - 1) ? 0.25f : 0.0f;

    int parity = tx & 1;
    float wA = parity ? 0.75f : 0.25f;
    float wB = parity ? 0.25f : 0.75f;

    int jbase = ox_base >> 1;
    int cb = (tx >> 1) + parity - 1;         // col offset of c0 within group 0
    int c0raw0 = jbase + cb;                 // lane tx=0 block 0 gives -1
    float mL = (c0raw0 >= 0) ? 1.0f : 0.0f;

    // ---- load phase: 32 unconditional loads into registers ----
    float A[4][4][2];                        // [g][row][col01]
#pragma unroll
    for (int g = 0; g < 4; ++g) {
        int c0r = jbase + 32 * g + cb;
        int c0 = c0r < 0 ? 0 : (c0r > W - 1 ? W - 1 : c0r);
        int c1 = (c0r + 1 > W - 1) ? W - 1 : c0r + 1;   // c0r+1 >= 0 always
        A[g][0][0] = r0[c0]; A[g][0][1] = r0[c1];
        A[g][1][0] = r1[c0]; A[g][1][1] = r1[c1];
        A[g][2][0] = r2[c0]; A[g][2][1] = r2[c1];
        A[g][3][0] = r3[c0]; A[g][3][1] = r3[c1];
    }
    // left-edge column mask (group 0, c0 side only)
    A[0][0][0] *= mL; A[0][1][0] *= mL; A[0][2][0] *= mL; A[0][3][0] *= mL;

    // ---- compute + store ----
#pragma unroll
    for (int g = 0; g < 4; ++g) {
        float v00 = w0    * A[g][0][0] + 0.75f * A[g][1][0];   // row oy0 (even)
        float v01 = w0    * A[g][0][1] + 0.75f * A[g][1][1];
        float v10 = 0.75f * A[g][1][0] + 0.25f * A[g][2][0];   // row oy0+1 (odd)
        float v11 = 0.75f * A[g][1][1] + 0.25f * A[g][2][1];
        float v20 = 0.25f * A[g][1][0] + 0.75f * A[g][2][0];   // row oy0+2 (even)
        float v21 = 0.25f * A[g][1][1] + 0.75f * A[g][2][1];
        float v30 = 0.75f * A[g][2][0] + w3    * A[g][3][0];   // row oy0+3 (odd)
        float v31 = 0.75f * A[g][2][1] + w3    * A[g][3][1];

        int ox = ox_base + 64 * g + tx;
        if (ox < Wo) {
            float* op = out + obase + (size_t)oy0 * Wo + ox;
            op[0] = wA * v00 + wB * v01;
            if (oy0 + 1 < Ho) op[Wo]     = wA * v10 + wB * v11;
            if (oy0 + 2 < Ho) op[2 * Wo] = wA * v20 + wB * v21;
            if (oy0 + 3 < Ho) op[3 * Wo] = wA * v30 + wB * v31;
        }
    }
}

extern "C" void kernel_launch(void* const* d_in, const int* in_sizes, int n_in,
                              void* d_out, int out_size, void* d_ws, size_t ws_size,
                              hipStream_t stream) {
    const float* x = (const float*)d_in[0];
    float* out = (float*)d_out;

    const int H = 256, W = 256;
    int NC = in_sizes[0] / (H * W);  // 256

    int hw_out = out_size / NC;
    int Wo = (int)(sqrt((double)hw_out) + 0.5);
    int Ho = hw_out / Wo;

    dim3 block(64, 4);
    dim3 grid((Wo + 255) / 256, (Ho + 15) / 16, NC);
    blur_up2_kernel<<<grid, block, 0, stream>>>(x, out, H, W, Ho, Wo);
}

// Round 6
// 92.761 us; speedup vs baseline: 1.6668x; 1.1152x over previous
//
#include <hip/hip_runtime.h>
#include <math.h>

// StyleGAN2 2x upsample blur (upfirdn2d, up=2, f=[1,3,3,1], gain=4).
// Separable: g=[0.25,0.75,0.75,0.25] per axis.
//   out[2i]   = 0.25*X[i-1] + 0.75*X[i]
//   out[2i+1] = 0.75*X[i]   + 0.25*X[i+1]
//
// One wave (64 lanes) = one input row i -> output rows {2i, 2i+1}, full width.
// Lane l loads float4 from rows i-1,i,i+1 at cols 4l..4l+3 (rows are 1KB
// aligned). Vertical blend -> ve[4], vo[4]. Horizontal halo via __shfl.
// Lane l produces 8 contiguous out cols 8l..8l+7 per row. Output rows have
// odd stride Wo=511, so each row's float4 alignment shift s=(4-(base&3))&3
// is applied by rotating values across lanes (<=3 shfl, s is wave-uniform,
// compile-time specialized) -> two aligned float4 stores/lane/row + tiny
// scalar fringes on lanes 0 and 63.

template<int S>
__device__ __forceinline__ void store_row_s(float* __restrict__ rp, int lane,
                                            int Wo, const float (&v8)[8]) {
    float n0 = 0.f, n1 = 0.f, n2 = 0.f;
    if (S >= 1) n0 = __shfl_down(v8[0], 1);
    if (S >= 2) n1 = __shfl_down(v8[1], 1);
    if (S >= 3) n2 = __shfl_down(v8[2], 1);
    float q[8];
#pragma unroll
    for (int k = 0; k < 8; ++k) {
        int idx = S + k;  // compile-time after unroll
        q[k] = (idx < 8) ? v8[idx] : (idx == 8 ? n0 : (idx == 9 ? n1 : n2));
    }
    int c0 = S + 8 * lane;  // 16B-aligned within row by construction
    if (lane < 63) {
        *(float4*)(rp + c0)     = make_float4(q[0], q[1], q[2], q[3]);
        *(float4*)(rp + c0 + 4) = make_float4(q[4], q[5], q[6], q[7]);
    } else {
        // cols S+504..S+507 are always < Wo (<=510); tail is partial
        *(float4*)(rp + c0) = make_float4(q[0], q[1], q[2], q[3]);
        if (c0 + 4 < Wo) rp[c0 + 4] = q[4];
        if (c0 + 5 < Wo) rp[c0 + 5] = q[5];
        if (c0 + 6 < Wo) rp[c0 + 6] = q[6];
        if (c0 + 7 < Wo) rp[c0 + 7] = q[7];
    }
    if (S > 0 && lane == 0) {   // left fringe cols 0..S-1
        rp[0] = v8[0];
        if (S > 1) rp[1] = v8[1];
        if (S > 2) rp[2] = v8[2];
    }
}

__device__ __forceinline__ void store_row(float* __restrict__ out, size_t rbase,
                                          int lane, int Wo, const float (&v8)[8]) {
    float* rp = out + rbase;
    int s = (int)((4 - (rbase & 3)) & 3);  // wave-uniform
    switch (s) {
        case 0:  store_row_s<0>(rp, lane, Wo, v8); break;
        case 1:  store_row_s<1>(rp, lane, Wo, v8); break;
        case 2:  store_row_s<2>(rp, lane, Wo, v8); break;
        default: store_row_s<3>(rp, lane, Wo, v8); break;
    }
}

__global__ __launch_bounds__(256) void blur_up2_kernel(
    const float* __restrict__ x, float* __restrict__ out,
    int H, int W, int Ho, int Wo) {
    int lane = threadIdx.x;                    // 0..63
    int i = blockIdx.y * 4 + threadIdx.y;      // input row index
    int nc = blockIdx.z;
    if (i >= H) return;

    const float* xp = x + (size_t)nc * H * W;
    int im = i > 0 ? i - 1 : 0;
    int ip = i < H - 1 ? i + 1 : H - 1;
    const float4* rm = (const float4*)(xp + im * W);
    const float4* rc = (const float4*)(xp + i * W);
    const float4* rpl = (const float4*)(xp + ip * W);
    float w0 = (i > 0)     ? 0.25f : 0.0f;     // row masks folded into weights
    float wp = (i < H - 1) ? 0.25f : 0.0f;

    float4 a = rm[lane];
    float4 b = rc[lane];
    float4 c = rpl[lane];

    // vertical blend: ve -> out row 2i, vo -> out row 2i+1
    float ve[4], vo[4];
    ve[0] = w0 * a.x + 0.75f * b.x;  vo[0] = 0.75f * b.x + wp * c.x;
    ve[1] = w0 * a.y + 0.75f * b.y;  vo[1] = 0.75f * b.y + wp * c.y;
    ve[2] = w0 * a.z + 0.75f * b.z;  vo[2] = 0.75f * b.z + wp * c.z;
    ve[3] = w0 * a.w + 0.75f * b.w;  vo[3] = 0.75f * b.w + wp * c.w;

    // horizontal halos: h[4l-1] from lane-1, h[4l+4] from lane+1
    float vem = __shfl_up(ve[3], 1);
    float vom = __shfl_up(vo[3], 1);
    if (lane == 0) { vem = 0.f; vom = 0.f; }   // col -1 contributes 0
    float vep = __shfl_down(ve[0], 1);         // lane 63: garbage, never stored
    float vop = __shfl_down(vo[0], 1);

    // horizontal blend: 8 contiguous out cols per row
    float e8[8], o8[8];
    e8[0] = 0.25f * vem   + 0.75f * ve[0];   o8[0] = 0.25f * vom   + 0.75f * vo[0];
    e8[1] = 0.75f * ve[0] + 0.25f * ve[1];   o8[1] = 0.75f * vo[0] + 0.25f * vo[1];
    e8[2] = 0.25f * ve[0] + 0.75f * ve[1];   o8[2] = 0.25f * vo[0] + 0.75f * vo[1];
    e8[3] = 0.75f * ve[1] + 0.25f * ve[2];   o8[3] = 0.75f * vo[1] + 0.25f * vo[2];
    e8[4] = 0.25f * ve[1] + 0.75f * ve[2];   o8[4] = 0.25f * vo[1] + 0.75f * vo[2];
    e8[5] = 0.75f * ve[2] + 0.25f * ve[3];   o8[5] = 0.75f * vo[2] + 0.25f * vo[3];
    e8[6] = 0.25f * ve[2] + 0.75f * ve[3];   o8[6] = 0.25f * vo[2] + 0.75f * vo[3];
    e8[7] = 0.75f * ve[3] + 0.25f * vep;     o8[7] = 0.75f * vo[3] + 0.25f * vop;

    size_t obase = (size_t)nc * Ho * Wo;
    store_row(out, obase + (size_t)(2 * i) * Wo, lane, Wo, e8);
    if (2 * i + 1 < Ho)
        store_row(out, obase + (size_t)(2 * i + 1) * Wo, lane, Wo, o8);
}

extern "C" void kernel_launch(void* const* d_in, const int* in_sizes, int n_in,
                              void* d_out, int out_size, void* d_ws, size_t ws_size,
                              hipStream_t stream) {
    const float* x = (const float*)d_in[0];
    float* out = (float*)d_out;

    const int H = 256, W = 256;
    int NC = in_sizes[0] / (H * W);  // 256

    int hw_out = out_size / NC;
    int Wo = (int)(sqrt((double)hw_out) + 0.5);
    int Ho = hw_out / Wo;

    dim3 block(64, 4);
    dim3 grid(1, (H + 3) / 4, NC);
    blur_up2_kernel<<<grid, block, 0, stream>>>(x, out, H, W, Ho, Wo);
}